// Round 1
// baseline (383.328 us; speedup 1.0000x reference)
//
#include <hip/hip_runtime.h>
#include <stdint.h>

typedef unsigned short u16;
typedef unsigned int u32;
typedef __attribute__((ext_vector_type(8))) short bf16x8;
typedef __attribute__((ext_vector_type(4))) short bf16x4;
typedef __attribute__((ext_vector_type(4))) float f32x4;

#define DD 128
#define CAP 64     // Poisson(16): P(deg>64) ~ 1e-20; overflow path still correct
#define STRA 136   // A-tile LDS stride (u16): 272B rows, 16B-aligned
#define STRC1 264  // C-tile stride (u16)
#define STRCF 132  // k5/k6 C-tile stride (f32)

__device__ __forceinline__ float bflo(u32 u){ return __uint_as_float(u<<16); }
__device__ __forceinline__ float bfhi(u32 u){ return __uint_as_float(u & 0xffff0000u); }
__device__ __forceinline__ float bf2f(u16 u){ return __uint_as_float(((u32)u)<<16); }
__device__ __forceinline__ u16 f2bf(float f){
  u32 u = __float_as_uint(f);
  return (u16)((u + 0x7fffu + ((u>>16)&1u)) >> 16);   // RNE
}

#define FMA8(g, vv) do { \
    acc[0] += (vv)*bflo((g).x); acc[1] += (vv)*bfhi((g).x); \
    acc[2] += (vv)*bflo((g).y); acc[3] += (vv)*bfhi((g).y); \
    acc[4] += (vv)*bflo((g).z); acc[5] += (vv)*bfhi((g).z); \
    acc[6] += (vv)*bflo((g).w); acc[7] += (vv)*bfhi((g).w); } while(0)

// kU: fused init. (a) zero control region (COMPUTE kernel, never memset-node —
// graph replay ordering), (b) pre-swizzle weights into MFMA B-fragment order,
// (c) build gather table T[r] = [bf16(x_r) (128) | bf16(perb_r) (128)].
// All writes disjoint; no intra-kernel ordering needed.
__global__ __launch_bounds__(256) void kU_init(
    const float* __restrict__ x, const float* __restrict__ perb,
    const float* __restrict__ W, const float* __restrict__ Wt,
    const float* __restrict__ W1, const float* __restrict__ W2,
    u16* __restrict__ T, u16* __restrict__ Bswz,
    u16* __restrict__ W1swz, u16* __restrict__ W2swz,
    int* __restrict__ deg, float* __restrict__ stats,
    float* __restrict__ gbuf, int N)
{
  int f = blockIdx.x*256 + threadIdx.x;
  // --- kZ part ---
  if (f < N) deg[f] = 0;
  if (f < 512) stats[f] = 0.f;
  if (f < 64) gbuf[f] = 0.f;   // covers gloss + ovfc + ticket (256B block)
  // --- k0 part (weight swizzle) ---
  if (f < 65536) {
    int idx = f;
    if (idx < 32768) {
      int j = idx & 7, lane = (idx>>3)&63, nt = (idx>>9)&15, kt = idx>>13;
      int k = kt*32 + (lane>>4)*8 + j, n = nt*16 + (lane&15);
      float v = (n < DD) ? W[k*DD + n] : Wt[k*DD + (n-DD)];
      Bswz[idx] = f2bf(v);
    } else {
      int t = idx - 32768;
      int which = t >> 14; t &= 16383;
      int j = t & 7, lane = (t>>3)&63, nt = (t>>9)&7, kt = (t>>12)&3;
      int k = kt*32 + (lane>>4)*8 + j, n = nt*16 + (lane&15);
      const float* __restrict__ src = which ? W2 : W1;
      u16* __restrict__ dst = which ? W2swz : W1swz;
      dst[t] = f2bf(src[k*DD + n]);
    }
  }
  // --- kT part (gather table) ---
  if (f < N*32) {
    int r = f >> 5, c8 = f & 31;
    const float* src = (c8 < 16) ? (x + (size_t)r*DD + c8*8)
                                 : (perb + (size_t)r*DD + (c8-16)*8);
    float4 a = *(const float4*)src;
    float4 bq = *(const float4*)(src + 4);
    bf16x8 o;
    o[0]=(short)f2bf(a.x); o[1]=(short)f2bf(a.y); o[2]=(short)f2bf(a.z); o[3]=(short)f2bf(a.w);
    o[4]=(short)f2bf(bq.x); o[5]=(short)f2bf(bq.y); o[6]=(short)f2bf(bq.z); o[7]=(short)f2bf(bq.w);
    *(bf16x8*)(T + (size_t)r*256 + c8*8) = o;
  }
}

// K2: bucket edges by destination row, storing packed (col, val).
__global__ __launch_bounds__(256) void k2_bucket(
    const int* __restrict__ row, const int* __restrict__ col,
    const float* __restrict__ val, int E, int* __restrict__ deg,
    int2* __restrict__ perm, int* __restrict__ ovfc, int* __restrict__ ovf)
{
  int e = blockIdx.x*256 + threadIdx.x;
  if (e >= E) return;
  int r = row[e];
  int slot = atomicAdd(&deg[r], 1);
  if (slot < CAP) {
    int2 cv; cv.x = col[e]; cv.y = __float_as_int(val[e]);
    perm[(size_t)r*CAP + slot] = cv;
  }
  else { int oi = atomicAdd(ovfc, 1); if (oi < 4096) ovf[oi] = e; }
}

// K3: one wave per row. dwordx4 gathers: 32 lanes cover one 512B T-row (16B/lane),
// the two wave-halves process even/odd edges -> 1 VMEM instr per 2 edges,
// 4 loads (8 edges) kept in flight per iteration.
// Output T2[r] = [aggx1 (128) | aggx2=aggx1+aggp (128)] bf16 (no bias).
__global__ __launch_bounds__(256) void k3_spmm(
    const int2* __restrict__ perm, const int* __restrict__ deg,
    const u16* __restrict__ T, u16* __restrict__ T2, int N)
{
  int row = blockIdx.x*4 + (threadIdx.x >> 6);
  int l = threadIdx.x & 63;
  if (row >= N) return;
  int dg = deg[row];
  dg = dg < 0 ? 0 : (dg > CAP ? CAP : dg);       // defensive clamp
  const int half = l >> 5, hl = l & 31;
  const int eoff = hl * 8;                        // elem offset in 256-wide T row
  float acc[8] = {0.f,0.f,0.f,0.f,0.f,0.f,0.f,0.f};
  for (int base = 0; base < dg; base += 64) {
    int2 ev = make_int2(0, 0);                    // pad: c=0, v=0 (harmless gather)
    if (base + l < dg) ev = perm[(size_t)row*CAP + base + l];
    int c = ev.x; float v = __int_as_float(ev.y);
    c = ((unsigned)c < (unsigned)N) ? c : 0;      // defensive clamp (no wild OOB)
    int mm = dg - base; if (mm > 64) mm = 64;
    int kmax = (mm + 1) & ~1;                     // round up to even (pad v=0)
    int j = 0;
    for (; j + 8 <= kmax; j += 8) {
      int i0 = j + half, i1 = j + 2 + half, i2 = j + 4 + half, i3 = j + 6 + half;
      int   c0 = __shfl(c, i0), c1 = __shfl(c, i1);
      int   c2 = __shfl(c, i2), c3 = __shfl(c, i3);
      float v0 = __shfl(v, i0), v1 = __shfl(v, i1);
      float v2 = __shfl(v, i2), v3 = __shfl(v, i3);
      uint4 g0 = *(const uint4*)(T + (size_t)c0*256 + eoff);
      uint4 g1 = *(const uint4*)(T + (size_t)c1*256 + eoff);
      uint4 g2 = *(const uint4*)(T + (size_t)c2*256 + eoff);
      uint4 g3 = *(const uint4*)(T + (size_t)c3*256 + eoff);
      FMA8(g0, v0); FMA8(g1, v1); FMA8(g2, v2); FMA8(g3, v3);
    }
    for (; j < kmax; j += 2) {
      int i0 = j + half;
      int   c0 = __shfl(c, i0);
      float v0 = __shfl(v, i0);
      uint4 g0 = *(const uint4*)(T + (size_t)c0*256 + eoff);
      FMA8(g0, v0);
    }
  }
  // combine even/odd-edge partials across halves
  #pragma unroll
  for (int i = 0; i < 8; ++i) acc[i] += __shfl_xor(acc[i], 32);
  // hl<16 holds x-part elems (aggx1), hl>=16 holds perb-part elems;
  // aggx2[e] = aggx1[e] + aggp[e]: fetch partner-x from lane hl-16.
  int sel = (hl >= 16) ? (hl - 16) : hl;
  bf16x8 ob;
  #pragma unroll
  for (int i = 0; i < 8; ++i) {
    float xv = __shfl(acc[i], sel);
    float o = (hl < 16) ? acc[i] : (xv + acc[i]);
    ob[i] = (short)f2bf(o);
  }
  if (half == 0)
    *(bf16x8*)(T2 + (size_t)row*256 + hl*8) = ob;   // 32 lanes x 16B = 512B row
}

// K3b: overflow fallback (expected empty) — serial RMW on T2.
__global__ __launch_bounds__(256) void k3b_ovf(
    const int* __restrict__ rowI, const int* __restrict__ colI,
    const float* __restrict__ val, const int* __restrict__ ovfc,
    const int* __restrict__ ovf, const u16* __restrict__ T,
    u16* __restrict__ T2)
{
  int n = *ovfc; if (n > 4096) n = 4096;
  for (int i = 0; i < n; ++i) {
    int e = ovf[i];
    int r = rowI[e], c = colI[e];
    float v = val[e];
    int d = threadIdx.x;           // 256 threads cover the 256-wide row
    int dl = d & 127;
    float add = v * bf2f(T[(size_t)c*256 + dl]);
    if (d >= 128) add += v * bf2f(T[(size_t)c*256 + 128 + dl]);
    u16* p = &T2[(size_t)r*256 + d];
    *p = f2bf(bf2f(*p) + add);
  }
}

// K4: dense MFMA GEMM [aggx1;aggx2] @ [W|Wt] + bias -> AGGb (bf16);
// embed = x+perb+s2 written fp32, with x+perb taken from the bf16 table T
// (saves the 51.2MB fp32 re-read of x,perb).
__global__ __launch_bounds__(256) void k4_gemm(
    const u16* __restrict__ T2, const u16* __restrict__ Bswz,
    const float* __restrict__ b, const float* __restrict__ bt,
    const u16* __restrict__ T,
    u16* __restrict__ AGGb, float* __restrict__ outE, int N)
{
  __shared__ __align__(16) u16 As[64*STRA];
  __shared__ __align__(16) u16 Cs[64*STRC1];
  const int tid = threadIdx.x;
  const int r0 = blockIdx.x * 32;
  #pragma unroll
  for (int i = 0; i < 4; ++i) {
    int f = tid + 256*i;            // 1024 chunks: 64 A-rows x 16 chunks of 8
    int row = f >> 4, c8 = f & 15;
    int r = r0 + (row & 31);
    bf16x8 ch = {0,0,0,0,0,0,0,0};
    if (r < N) ch = *(const bf16x8*)(T2 + (size_t)r*256 + (row>>5)*128 + c8*8);
    *(bf16x8*)&As[row*STRA + c8*8] = ch;
  }
  __syncthreads();
  const int w = tid >> 6, l = tid & 63;
  const int m = l & 15, q = l >> 4;
  f32x4 acc[16];
  #pragma unroll
  for (int nt = 0; nt < 16; ++nt) acc[nt] = (f32x4){0.f,0.f,0.f,0.f};
  const int arow = w*16 + m;
  #pragma unroll
  for (int kt = 0; kt < 4; ++kt) {
    bf16x8 af = *(const bf16x8*)&As[arow*STRA + kt*32 + q*8];
    #pragma unroll
    for (int nt = 0; nt < 16; ++nt) {
      bf16x8 bf = *(const bf16x8*)(Bswz + ((size_t)(kt*16+nt)*64 + l)*8);
      acc[nt] = __builtin_amdgcn_mfma_f32_16x16x32_bf16(af, bf, acc[nt], 0, 0, 0);
    }
  }
  #pragma unroll
  for (int nt = 0; nt < 16; ++nt) {
    int n = nt*16 + m;
    float bv = (n < 128) ? b[n] : bt[n-128];
    #pragma unroll
    for (int i = 0; i < 4; ++i)
      Cs[(w*16 + q*4 + i)*STRC1 + nt*16 + m] = f2bf(acc[nt][i] + bv);
  }
  __syncthreads();
  {
    const int ar = tid >> 2, p = tid & 3;
    const int src = r0 + (ar & 31);
    if (src < N) {
      size_t grow = (size_t)src*2 + (ar >> 5);  // even: [s0|s1], odd: [s2|s3]
      const u16* sp = &Cs[ar*STRC1 + p*64];
      u16* dp = AGGb + grow*256 + p*64;
      #pragma unroll
      for (int i = 0; i < 8; ++i)
        *(bf16x8*)(dp + i*8) = *(const bf16x8*)(sp + i*8);
    }
  }
  // embed = x + perb + s2 (s2 = rows 32-63 of Cs, bias included); x,perb from T (bf16)
  #pragma unroll
  for (int i = 0; i < 2; ++i) {
    int f = tid + 256*i;            // 512 chunks: 32 rows x 16 chunks of 8
    int rr = f >> 4, c8 = f & 15;
    int src = r0 + rr;
    if (src < N) {
      const u16* cp = &Cs[(32+rr)*STRC1 + c8*8];
      bf16x8 xv = *(const bf16x8*)(T + (size_t)src*256 + c8*8);
      bf16x8 pv = *(const bf16x8*)(T + (size_t)src*256 + 128 + c8*8);
      bf16x8 cv = *(const bf16x8*)cp;
      float4 e0, e1;
      e0.x = bf2f((u16)xv[0])+bf2f((u16)pv[0])+bf2f((u16)cv[0]);
      e0.y = bf2f((u16)xv[1])+bf2f((u16)pv[1])+bf2f((u16)cv[1]);
      e0.z = bf2f((u16)xv[2])+bf2f((u16)pv[2])+bf2f((u16)cv[2]);
      e0.w = bf2f((u16)xv[3])+bf2f((u16)pv[3])+bf2f((u16)cv[3]);
      e1.x = bf2f((u16)xv[4])+bf2f((u16)pv[4])+bf2f((u16)cv[4]);
      e1.y = bf2f((u16)xv[5])+bf2f((u16)pv[5])+bf2f((u16)cv[5]);
      e1.z = bf2f((u16)xv[6])+bf2f((u16)pv[6])+bf2f((u16)cv[6]);
      e1.w = bf2f((u16)xv[7])+bf2f((u16)pv[7])+bf2f((u16)cv[7]);
      float* er = outE + (size_t)src*DD + c8*8;
      *(float4*)er = e0;
      *(float4*)(er+4) = e1;
    }
  }
}

// K5: P = AGG_seg @ W1 + b1 (MFMA); per-block BN partials (no atomics); P bf16.
__global__ __launch_bounds__(256) void k5_gemm(
    const u16* __restrict__ AGGb, const u16* __restrict__ W1swz,
    const float* __restrict__ b1, u16* __restrict__ Px, u16* __restrict__ Py,
    float* __restrict__ partial, int N)
{
  __shared__ __align__(16) u16 As[64*STRA];
  __shared__ __align__(16) float Cs[64*STRCF];
  const int tid = threadIdx.x;
  const int seg = blockIdx.y;
  const int soff = seg ? 256 : 0;   // seg0 (online_x) or seg2 (online_y)
  const int r0 = blockIdx.x * 64;
  #pragma unroll
  for (int i = 0; i < 4; ++i) {
    int f = tid + 256*i;
    int row = f >> 4, c8 = f & 15;
    int r = r0 + row;
    bf16x8 ch = {0,0,0,0,0,0,0,0};
    if (r < N) ch = *(const bf16x8*)(AGGb + (size_t)r*512 + soff + c8*8);
    *(bf16x8*)&As[row*STRA + c8*8] = ch;
  }
  __syncthreads();
  const int w = tid >> 6, l = tid & 63;
  const int m = l & 15, q = l >> 4;
  f32x4 acc[8];
  #pragma unroll
  for (int nt = 0; nt < 8; ++nt) acc[nt] = (f32x4){0.f,0.f,0.f,0.f};
  const int arow = w*16 + m;
  #pragma unroll
  for (int kt = 0; kt < 4; ++kt) {
    bf16x8 af = *(const bf16x8*)&As[arow*STRA + kt*32 + q*8];
    #pragma unroll
    for (int nt = 0; nt < 8; ++nt) {
      bf16x8 bf = *(const bf16x8*)(W1swz + ((size_t)(kt*8+nt)*64 + l)*8);
      acc[nt] = __builtin_amdgcn_mfma_f32_16x16x32_bf16(af, bf, acc[nt], 0, 0, 0);
    }
  }
  const int rbase = r0 + w*16 + q*4;
  float* red = Cs;    // scratch: [type][wave*128 + col]
  #pragma unroll
  for (int nt = 0; nt < 8; ++nt) {
    float bv = b1[nt*16 + m];
    float sum = 0.f, sq = 0.f;
    #pragma unroll
    for (int i = 0; i < 4; ++i) {
      if (rbase + i < N) acc[nt][i] += bv; else acc[nt][i] = 0.f;
      sum += acc[nt][i]; sq += acc[nt][i]*acc[nt][i];
    }
    sum += __shfl_xor(sum, 16); sum += __shfl_xor(sum, 32);
    sq  += __shfl_xor(sq, 16);  sq  += __shfl_xor(sq, 32);
    if (l < 16) {
      red[      w*128 + nt*16 + l] = sum;
      red[512 + w*128 + nt*16 + l] = sq;
    }
  }
  __syncthreads();
  {
    int type = tid >> 7, col = tid & 127;
    float v = red[type*512 + col] + red[type*512 + 128 + col]
            + red[type*512 + 256 + col] + red[type*512 + 384 + col];
    partial[((size_t)seg*gridDim.x + blockIdx.x)*256 + tid] = v;
  }
  __syncthreads();
  #pragma unroll
  for (int nt = 0; nt < 8; ++nt)
    #pragma unroll
    for (int i = 0; i < 4; ++i)
      Cs[(w*16 + q*4 + i)*STRCF + nt*16 + m] = acc[nt][i];
  __syncthreads();
  const int ar = tid >> 2, p = tid & 3;
  const int r = r0 + ar;
  u16* __restrict__ P = seg ? Py : Px;
  if (r < N) {
    const float* sp = &Cs[ar*STRCF + p*32];
    u16* dp = P + (size_t)r*DD + p*32;
    #pragma unroll
    for (int i = 0; i < 4; ++i) {
      bf16x8 ob;
      #pragma unroll
      for (int t2 = 0; t2 < 8; ++t2) ob[t2] = (short)f2bf(sp[i*8+t2]);
      *(bf16x8*)(dp + i*8) = ob;
    }
  }
}

// K5b: reduce per-block partials into stats (few atomics).
__global__ __launch_bounds__(256) void k5b_stats(
    const float* __restrict__ partial, float* __restrict__ stats, int nb)
{
  int seg = blockIdx.y, chunk = blockIdx.x, t = threadIdx.x;
  int per = (nb + gridDim.x - 1) / gridDim.x;
  int lo = chunk*per, hi = lo+per; if (hi > nb) hi = nb;
  float s = 0.f;
  const float* p = partial + (size_t)seg*nb*256;
  for (int i = lo; i < hi; ++i) s += p[(size_t)i*256 + t];
  atomicAdd(&stats[seg*256 + t], s);
}

// K6: BN+PReLU (bf16 P) -> MFMA GEMM2 (+b2) -> per-row BYOL cosine ->
// 1 atomic/block; last block (device-scope ticket) finalizes loss (fused k7).
__global__ __launch_bounds__(256) void k6_gemm_loss(
    const u16* __restrict__ Px, const u16* __restrict__ Py,
    const u16* __restrict__ AGGb, const float* __restrict__ stats,
    const float* __restrict__ gamma, const float* __restrict__ beta,
    const float* __restrict__ aP, const u16* __restrict__ W2swz,
    const float* __restrict__ b2, float* __restrict__ gloss,
    float* __restrict__ outF, int* __restrict__ ticket, int N)
{
  __shared__ __align__(16) u16 As[64*STRA];
  __shared__ __align__(16) float Cs[64*STRCF];
  __shared__ float s1s[128], s2s[128];
  __shared__ float gred[4];
  const int tid = threadIdx.x;
  const int seg = blockIdx.y;
  const u16* __restrict__ P = seg ? Py : Px;
  const int toff = seg ? 128 : 384;  // seg0: target_x = s3; seg1: target_y = s1
  const float invN = 1.f / (float)N;
  if (tid < 128) {
    float mu = stats[seg*256 + tid] * invN;
    float var = stats[seg*256 + 128 + tid] * invN - mu*mu;
    float rstd = rsqrtf(var + 1e-5f);
    float s1 = rstd * gamma[tid];
    s1s[tid] = s1;
    s2s[tid] = beta[tid] - mu*s1;
  }
  const float alpha = aP[0];
  const int r0 = blockIdx.x * 64;
  __syncthreads();
  #pragma unroll
  for (int i = 0; i < 4; ++i) {
    int f = tid + 256*i;
    int row = f >> 4, c8 = f & 15;
    int r = r0 + row;
    bf16x8 ch = {0,0,0,0,0,0,0,0};
    if (r < N) ch = *(const bf16x8*)(P + (size_t)r*DD + c8*8);
    bf16x8 a;
    #pragma unroll
    for (int t2 = 0; t2 < 8; ++t2) {
      int colc = c8*8 + t2;
      float hv = bf2f((u16)ch[t2]);
      float hn = hv*s1s[colc] + s2s[colc];
      hn = hn >= 0.f ? hn : alpha*hn;
      a[t2] = (short)f2bf(hn);
    }
    *(bf16x8*)&As[row*STRA + c8*8] = a;
  }
  __syncthreads();
  const int w = tid >> 6, l = tid & 63;
  const int m = l & 15, q = l >> 4;
  f32x4 acc[8];
  #pragma unroll
  for (int nt = 0; nt < 8; ++nt) acc[nt] = (f32x4){0.f,0.f,0.f,0.f};
  const int arow = w*16 + m;
  #pragma unroll
  for (int kt = 0; kt < 4; ++kt) {
    bf16x8 af = *(const bf16x8*)&As[arow*STRA + kt*32 + q*8];
    #pragma unroll
    for (int nt = 0; nt < 8; ++nt) {
      bf16x8 bf = *(const bf16x8*)(W2swz + ((size_t)(kt*8+nt)*64 + l)*8);
      acc[nt] = __builtin_amdgcn_mfma_f32_16x16x32_bf16(af, bf, acc[nt], 0, 0, 0);
    }
  }
  #pragma unroll
  for (int nt = 0; nt < 8; ++nt) {
    float bv = b2[nt*16 + m];
    #pragma unroll
    for (int i = 0; i < 4; ++i)
      Cs[(w*16 + q*4 + i)*STRCF + nt*16 + m] = acc[nt][i] + bv;
  }
  __syncthreads();
  float lsum = 0.f;
  for (int rr = 0; rr < 16; ++rr) {
    int ar = w*16 + rr;
    int r = r0 + ar;
    if (r >= N) break;   // uniform within wave
    float2 pv = *(const float2*)&Cs[ar*STRCF + l*2];
    u32 tw = *(const u32*)(AGGb + (size_t)r*512 + toff + l*2);
    float t0 = bflo(tw), t1 = bfhi(tw);
    float pp = pv.x*pv.x + pv.y*pv.y;
    float tt = t0*t0 + t1*t1;
    float pt = pv.x*t0 + pv.y*t1;
    #pragma unroll
    for (int off = 1; off <= 32; off <<= 1) {
      pp += __shfl_xor(pp, off);
      tt += __shfl_xor(tt, off);
      pt += __shfl_xor(pt, off);
    }
    if (l == 0) lsum += 2.f - 2.f * pt * rsqrtf(pp * tt);
  }
  if (l == 0) gred[w] = lsum;
  __syncthreads();
  if (tid == 0) {
    atomicAdd(gloss, gred[0]+gred[1]+gred[2]+gred[3]);
    __threadfence();
    int old = atomicAdd(ticket, 1);
    if (old == 2*(int)gridDim.x - 1) {          // last of the 2*NB5 blocks
      float g = atomicAdd(gloss, 0.f);          // device-scope RMW: final sum
      outF[(size_t)N*DD] = g / (float)N;
    }
  }
}

extern "C" void kernel_launch(void* const* d_in, const int* in_sizes, int n_in,
                              void* d_out, int out_size, void* d_ws, size_t ws_size,
                              hipStream_t stream)
{
  const float* x    = (const float*)d_in[0];
  const float* perb = (const float*)d_in[1];
  const int*   erow = (const int*)d_in[2];
  const int*   ecol = (const int*)d_in[3];
  const float* eval_= (const float*)d_in[4];
  const float* W    = (const float*)d_in[5];
  const float* b    = (const float*)d_in[6];
  const float* Wt   = (const float*)d_in[7];
  const float* bt   = (const float*)d_in[8];
  const float* W1   = (const float*)d_in[9];
  const float* b1   = (const float*)d_in[10];
  const float* gam  = (const float*)d_in[11];
  const float* bet  = (const float*)d_in[12];
  const float* aP   = (const float*)d_in[13];
  const float* W2   = (const float*)d_in[14];
  const float* b2   = (const float*)d_in[15];
  const int N = in_sizes[0] / DD;
  const int E = in_sizes[2];
  const int NB5 = (N + 63)/64;

  char* ws = (char*)d_ws;
  size_t off = 0;
  auto alloc = [&](size_t bytes) -> void* {
    void* p = ws + off;
    off += (bytes + 255) & ~(size_t)255;
    return p;
  };
  u16*   AGGb = (u16*)  alloc((size_t)N*512*sizeof(u16));   // 51.2 MB (bf16)
  u16*   T    = (u16*)  alloc((size_t)N*256*sizeof(u16));   // 25.6 MB (reused as Px/Py)
  u16*   T2   = (u16*)  alloc((size_t)N*256*sizeof(u16));   // 25.6 MB
  int*   deg  = (int*)  alloc((size_t)N*sizeof(int));
  float* stats= (float*)alloc(512*sizeof(float));
  float* gloss= (float*)alloc(256);
  int*   ovfc = (int*)((char*)gloss + 64);
  int*   ticket = (int*)((char*)gloss + 128);
  int2*  perm = (int2*) alloc((size_t)N*CAP*sizeof(int2));  // 25.6 MB
  int*   ovf  = (int*)  alloc(4096*sizeof(int));
  u16*   Bswz = (u16*)  alloc(32768*sizeof(u16));
  u16*   W1swz= (u16*)  alloc(16384*sizeof(u16));
  u16*   W2swz= (u16*)  alloc(16384*sizeof(u16));
  float* partial = (float*)alloc((size_t)2*NB5*256*sizeof(float)); // 1.6 MB
  if (ws_size < off) return;

  u16* Px = T;                       // T dead after k4; 2 x 12.8 MB bf16
  u16* Py = Px + (size_t)N*DD;

  kU_init<<<(N*32 + 255)/256, 256, 0, stream>>>(x, perb, W, Wt, W1, W2,
                                                T, Bswz, W1swz, W2swz,
                                                deg, stats, gloss, N);
  k2_bucket<<<(E + 255)/256, 256, 0, stream>>>(erow, ecol, eval_, E, deg, perm, ovfc, ovf);
  k3_spmm<<<(N + 3)/4, 256, 0, stream>>>(perm, deg, T, T2, N);
  k3b_ovf<<<1, 256, 0, stream>>>(erow, ecol, eval_, ovfc, ovf, T, T2);
  k4_gemm<<<(N + 31)/32, 256, 0, stream>>>(T2, Bswz, b, bt, T, AGGb, (float*)d_out, N);
  k5_gemm<<<dim3(NB5, 2), 256, 0, stream>>>(AGGb, W1swz, b1, Px, Py, partial, N);
  k5b_stats<<<dim3(16, 2), 256, 0, stream>>>(partial, stats, NB5);
  k6_gemm_loss<<<dim3(NB5, 2), 256, 0, stream>>>(Px, Py, AGGb, stats, gam, bet, aP,
                                                 W2swz, b2, gloss, (float*)d_out, ticket, N);
}

// Round 3
// 334.048 us; speedup vs baseline: 1.1475x; 1.1475x over previous
//
#include <hip/hip_runtime.h>
#include <stdint.h>

typedef unsigned short u16;
typedef unsigned int u32;
typedef __attribute__((ext_vector_type(8))) short bf16x8;
typedef __attribute__((ext_vector_type(4))) short bf16x4;
typedef __attribute__((ext_vector_type(4))) float f32x4;

#define DD 128
#define CAP 64     // Poisson(16): P(deg>64) ~ 1e-20; overflow path still correct
#define STRA 136   // A-tile LDS stride (u16): 272B rows, 16B-aligned
#define STRC1 264  // C-tile stride (u16)
#define STRCF 132  // k5/k6 C-tile stride (f32)

__device__ __forceinline__ float bflo(u32 u){ return __uint_as_float(u<<16); }
__device__ __forceinline__ float bfhi(u32 u){ return __uint_as_float(u & 0xffff0000u); }
__device__ __forceinline__ float bf2f(u16 u){ return __uint_as_float(((u32)u)<<16); }
__device__ __forceinline__ u16 f2bf(float f){
  u32 u = __float_as_uint(f);
  return (u16)((u + 0x7fffu + ((u>>16)&1u)) >> 16);   // RNE
}

#define FMA8(g, vv) do { \
    acc[0] += (vv)*bflo((g).x); acc[1] += (vv)*bfhi((g).x); \
    acc[2] += (vv)*bflo((g).y); acc[3] += (vv)*bfhi((g).y); \
    acc[4] += (vv)*bflo((g).z); acc[5] += (vv)*bfhi((g).z); \
    acc[6] += (vv)*bflo((g).w); acc[7] += (vv)*bfhi((g).w); } while(0)

// kU: fused init. (a) zero control region (COMPUTE kernel, never SDMA/memset —
// graph replay ordering), (b) pre-swizzle weights into MFMA B-fragment order,
// (c) build gather table T[r] = [bf16(x_r) (128) | bf16(perb_r) (128)].
__global__ __launch_bounds__(256) void kU_init(
    const float* __restrict__ x, const float* __restrict__ perb,
    const float* __restrict__ W, const float* __restrict__ Wt,
    const float* __restrict__ W1, const float* __restrict__ W2,
    u16* __restrict__ T, u16* __restrict__ Bswz,
    u16* __restrict__ W1swz, u16* __restrict__ W2swz,
    int* __restrict__ deg, float* __restrict__ stats,
    float* __restrict__ gbuf, int N)
{
  int f = blockIdx.x*256 + threadIdx.x;
  if (f < N) deg[f] = 0;
  if (f < 512) stats[f] = 0.f;
  if (f < 64) gbuf[f] = 0.f;   // covers gloss + ovfc (256B block)
  if (f < 65536) {
    int idx = f;
    if (idx < 32768) {
      int j = idx & 7, lane = (idx>>3)&63, nt = (idx>>9)&15, kt = idx>>13;
      int k = kt*32 + (lane>>4)*8 + j, n = nt*16 + (lane&15);
      float v = (n < DD) ? W[k*DD + n] : Wt[k*DD + (n-DD)];
      Bswz[idx] = f2bf(v);
    } else {
      int t = idx - 32768;
      int which = t >> 14; t &= 16383;
      int j = t & 7, lane = (t>>3)&63, nt = (t>>9)&7, kt = (t>>12)&3;
      int k = kt*32 + (lane>>4)*8 + j, n = nt*16 + (lane&15);
      const float* __restrict__ src = which ? W2 : W1;
      u16* __restrict__ dst = which ? W2swz : W1swz;
      dst[t] = f2bf(src[k*DD + n]);
    }
  }
  if (f < N*32) {
    int r = f >> 5, c8 = f & 31;
    const float* src = (c8 < 16) ? (x + (size_t)r*DD + c8*8)
                                 : (perb + (size_t)r*DD + (c8-16)*8);
    float4 a = *(const float4*)src;
    float4 bq = *(const float4*)(src + 4);
    bf16x8 o;
    o[0]=(short)f2bf(a.x); o[1]=(short)f2bf(a.y); o[2]=(short)f2bf(a.z); o[3]=(short)f2bf(a.w);
    o[4]=(short)f2bf(bq.x); o[5]=(short)f2bf(bq.y); o[6]=(short)f2bf(bq.z); o[7]=(short)f2bf(bq.w);
    *(bf16x8*)(T + (size_t)r*256 + c8*8) = o;
  }
}

// K2: bucket edges by destination row, storing packed (col, val).
__global__ __launch_bounds__(256) void k2_bucket(
    const int* __restrict__ row, const int* __restrict__ col,
    const float* __restrict__ val, int E, int* __restrict__ deg,
    int2* __restrict__ perm, int* __restrict__ ovfc, int* __restrict__ ovf)
{
  int e = blockIdx.x*256 + threadIdx.x;
  if (e >= E) return;
  int r = row[e];
  int slot = atomicAdd(&deg[r], 1);
  if (slot < CAP) {
    int2 cv; cv.x = col[e]; cv.y = __float_as_int(val[e]);
    perm[(size_t)r*CAP + slot] = cv;
  }
  else { int oi = atomicAdd(ovfc, 1); if (oi < 4096) ovf[oi] = e; }
}

// K3: one wave per row. dwordx4 gathers: 32 lanes cover one 512B T-row (16B/lane),
// the two wave-halves process even/odd edges -> 1 VMEM instr per 2 edges,
// 4 loads (8 edges) kept in flight per iteration.
// Output T2[r] = [aggx1 (128) | aggx2=aggx1+aggp (128)] bf16 (no bias).
__global__ __launch_bounds__(256) void k3_spmm(
    const int2* __restrict__ perm, const int* __restrict__ deg,
    const u16* __restrict__ T, u16* __restrict__ T2, int N)
{
  int row = blockIdx.x*4 + (threadIdx.x >> 6);
  int l = threadIdx.x & 63;
  if (row >= N) return;
  int dg = deg[row];
  dg = dg < 0 ? 0 : (dg > CAP ? CAP : dg);       // defensive clamp
  const int half = l >> 5, hl = l & 31;
  const int eoff = hl * 8;                        // elem offset in 256-wide T row
  float acc[8] = {0.f,0.f,0.f,0.f,0.f,0.f,0.f,0.f};
  for (int base = 0; base < dg; base += 64) {
    int2 ev = make_int2(0, 0);                    // pad: c=0, v=0 (harmless gather)
    if (base + l < dg) ev = perm[(size_t)row*CAP + base + l];
    int c = ev.x; float v = __int_as_float(ev.y);
    c = ((unsigned)c < (unsigned)N) ? c : 0;      // defensive clamp (no wild OOB)
    int mm = dg - base; if (mm > 64) mm = 64;
    int kmax = (mm + 1) & ~1;                     // round up to even (pad v=0)
    int j = 0;
    for (; j + 8 <= kmax; j += 8) {
      int i0 = j + half, i1 = j + 2 + half, i2 = j + 4 + half, i3 = j + 6 + half;
      int   c0 = __shfl(c, i0), c1 = __shfl(c, i1);
      int   c2 = __shfl(c, i2), c3 = __shfl(c, i3);
      float v0 = __shfl(v, i0), v1 = __shfl(v, i1);
      float v2 = __shfl(v, i2), v3 = __shfl(v, i3);
      uint4 g0 = *(const uint4*)(T + (size_t)c0*256 + eoff);
      uint4 g1 = *(const uint4*)(T + (size_t)c1*256 + eoff);
      uint4 g2 = *(const uint4*)(T + (size_t)c2*256 + eoff);
      uint4 g3 = *(const uint4*)(T + (size_t)c3*256 + eoff);
      FMA8(g0, v0); FMA8(g1, v1); FMA8(g2, v2); FMA8(g3, v3);
    }
    for (; j < kmax; j += 2) {
      int i0 = j + half;
      int   c0 = __shfl(c, i0);
      float v0 = __shfl(v, i0);
      uint4 g0 = *(const uint4*)(T + (size_t)c0*256 + eoff);
      FMA8(g0, v0);
    }
  }
  // combine even/odd-edge partials across halves
  #pragma unroll
  for (int i = 0; i < 8; ++i) acc[i] += __shfl_xor(acc[i], 32);
  // hl<16 holds x-part elems (aggx1), hl>=16 holds perb-part elems;
  // aggx2[e] = aggx1[e] + aggp[e]: fetch partner-x from lane hl-16.
  int sel = (hl >= 16) ? (hl - 16) : hl;
  bf16x8 ob;
  #pragma unroll
  for (int i = 0; i < 8; ++i) {
    float xv = __shfl(acc[i], sel);
    float o = (hl < 16) ? acc[i] : (xv + acc[i]);
    ob[i] = (short)f2bf(o);
  }
  if (half == 0)
    *(bf16x8*)(T2 + (size_t)row*256 + hl*8) = ob;   // 32 lanes x 16B = 512B row
}

// K3b: overflow fallback (expected empty) — serial RMW on T2.
__global__ __launch_bounds__(256) void k3b_ovf(
    const int* __restrict__ rowI, const int* __restrict__ colI,
    const float* __restrict__ val, const int* __restrict__ ovfc,
    const int* __restrict__ ovf, const u16* __restrict__ T,
    u16* __restrict__ T2)
{
  int n = *ovfc; if (n > 4096) n = 4096;
  for (int i = 0; i < n; ++i) {
    int e = ovf[i];
    int r = rowI[e], c = colI[e];
    float v = val[e];
    int d = threadIdx.x;           // 256 threads cover the 256-wide row
    int dl = d & 127;
    float add = v * bf2f(T[(size_t)c*256 + dl]);
    if (d >= 128) add += v * bf2f(T[(size_t)c*256 + 128 + dl]);
    u16* p = &T2[(size_t)r*256 + d];
    *p = f2bf(bf2f(*p) + add);
  }
}

// K4: dense MFMA GEMM [aggx1;aggx2] @ [W|Wt] + bias -> AGGb (bf16);
// embed = x+perb+s2 written fp32, with x+perb taken from the bf16 table T.
__global__ __launch_bounds__(256) void k4_gemm(
    const u16* __restrict__ T2, const u16* __restrict__ Bswz,
    const float* __restrict__ b, const float* __restrict__ bt,
    const u16* __restrict__ T,
    u16* __restrict__ AGGb, float* __restrict__ outE, int N)
{
  __shared__ __align__(16) u16 As[64*STRA];
  __shared__ __align__(16) u16 Cs[64*STRC1];
  const int tid = threadIdx.x;
  const int r0 = blockIdx.x * 32;
  #pragma unroll
  for (int i = 0; i < 4; ++i) {
    int f = tid + 256*i;            // 1024 chunks: 64 A-rows x 16 chunks of 8
    int row = f >> 4, c8 = f & 15;
    int r = r0 + (row & 31);
    bf16x8 ch = {0,0,0,0,0,0,0,0};
    if (r < N) ch = *(const bf16x8*)(T2 + (size_t)r*256 + (row>>5)*128 + c8*8);
    *(bf16x8*)&As[row*STRA + c8*8] = ch;
  }
  __syncthreads();
  const int w = tid >> 6, l = tid & 63;
  const int m = l & 15, q = l >> 4;
  f32x4 acc[16];
  #pragma unroll
  for (int nt = 0; nt < 16; ++nt) acc[nt] = (f32x4){0.f,0.f,0.f,0.f};
  const int arow = w*16 + m;
  #pragma unroll
  for (int kt = 0; kt < 4; ++kt) {
    bf16x8 af = *(const bf16x8*)&As[arow*STRA + kt*32 + q*8];
    #pragma unroll
    for (int nt = 0; nt < 16; ++nt) {
      bf16x8 bf = *(const bf16x8*)(Bswz + ((size_t)(kt*16+nt)*64 + l)*8);
      acc[nt] = __builtin_amdgcn_mfma_f32_16x16x32_bf16(af, bf, acc[nt], 0, 0, 0);
    }
  }
  #pragma unroll
  for (int nt = 0; nt < 16; ++nt) {
    int n = nt*16 + m;
    float bv = (n < 128) ? b[n] : bt[n-128];
    #pragma unroll
    for (int i = 0; i < 4; ++i)
      Cs[(w*16 + q*4 + i)*STRC1 + nt*16 + m] = f2bf(acc[nt][i] + bv);
  }
  __syncthreads();
  {
    const int ar = tid >> 2, p = tid & 3;
    const int src = r0 + (ar & 31);
    if (src < N) {
      size_t grow = (size_t)src*2 + (ar >> 5);  // even: [s0|s1], odd: [s2|s3]
      const u16* sp = &Cs[ar*STRC1 + p*64];
      u16* dp = AGGb + grow*256 + p*64;
      #pragma unroll
      for (int i = 0; i < 8; ++i)
        *(bf16x8*)(dp + i*8) = *(const bf16x8*)(sp + i*8);
    }
  }
  // embed = x + perb + s2 (s2 = rows 32-63 of Cs, bias included); x,perb from T (bf16)
  #pragma unroll
  for (int i = 0; i < 2; ++i) {
    int f = tid + 256*i;            // 512 chunks: 32 rows x 16 chunks of 8
    int rr = f >> 4, c8 = f & 15;
    int src = r0 + rr;
    if (src < N) {
      const u16* cp = &Cs[(32+rr)*STRC1 + c8*8];
      bf16x8 xv = *(const bf16x8*)(T + (size_t)src*256 + c8*8);
      bf16x8 pv = *(const bf16x8*)(T + (size_t)src*256 + 128 + c8*8);
      bf16x8 cv = *(const bf16x8*)cp;
      float4 e0, e1;
      e0.x = bf2f((u16)xv[0])+bf2f((u16)pv[0])+bf2f((u16)cv[0]);
      e0.y = bf2f((u16)xv[1])+bf2f((u16)pv[1])+bf2f((u16)cv[1]);
      e0.z = bf2f((u16)xv[2])+bf2f((u16)pv[2])+bf2f((u16)cv[2]);
      e0.w = bf2f((u16)xv[3])+bf2f((u16)pv[3])+bf2f((u16)cv[3]);
      e1.x = bf2f((u16)xv[4])+bf2f((u16)pv[4])+bf2f((u16)cv[4]);
      e1.y = bf2f((u16)xv[5])+bf2f((u16)pv[5])+bf2f((u16)cv[5]);
      e1.z = bf2f((u16)xv[6])+bf2f((u16)pv[6])+bf2f((u16)cv[6]);
      e1.w = bf2f((u16)xv[7])+bf2f((u16)pv[7])+bf2f((u16)cv[7]);
      float* er = outE + (size_t)src*DD + c8*8;
      *(float4*)er = e0;
      *(float4*)(er+4) = e1;
    }
  }
}

// K5: P = AGG_seg @ W1 + b1 (MFMA); per-block BN partials (no atomics); P bf16.
// LDS: As unioned with Cs (As dead after MFMA loop) -> 33.8KB -> 4 blocks/CU.
__global__ __launch_bounds__(256) void k5_gemm(
    const u16* __restrict__ AGGb, const u16* __restrict__ W1swz,
    const float* __restrict__ b1, u16* __restrict__ Px, u16* __restrict__ Py,
    float* __restrict__ partial, int N)
{
  __shared__ __align__(16) float Cs[64*STRCF];   // 33792B; aliased as As (17408B)
  u16* As = (u16*)Cs;
  const int tid = threadIdx.x;
  const int seg = blockIdx.y;
  const int soff = seg ? 256 : 0;   // seg0 (online_x) or seg2 (online_y)
  const int r0 = blockIdx.x * 64;
  #pragma unroll
  for (int i = 0; i < 4; ++i) {
    int f = tid + 256*i;
    int row = f >> 4, c8 = f & 15;
    int r = r0 + row;
    bf16x8 ch = {0,0,0,0,0,0,0,0};
    if (r < N) ch = *(const bf16x8*)(AGGb + (size_t)r*512 + soff + c8*8);
    *(bf16x8*)&As[row*STRA + c8*8] = ch;
  }
  __syncthreads();
  const int w = tid >> 6, l = tid & 63;
  const int m = l & 15, q = l >> 4;
  f32x4 acc[8];
  #pragma unroll
  for (int nt = 0; nt < 8; ++nt) acc[nt] = (f32x4){0.f,0.f,0.f,0.f};
  const int arow = w*16 + m;
  #pragma unroll
  for (int kt = 0; kt < 4; ++kt) {
    bf16x8 af = *(const bf16x8*)&As[arow*STRA + kt*32 + q*8];
    #pragma unroll
    for (int nt = 0; nt < 8; ++nt) {
      bf16x8 bf = *(const bf16x8*)(W1swz + ((size_t)(kt*8+nt)*64 + l)*8);
      acc[nt] = __builtin_amdgcn_mfma_f32_16x16x32_bf16(af, bf, acc[nt], 0, 0, 0);
    }
  }
  __syncthreads();                  // As dead; red (=Cs) writes follow
  const int rbase = r0 + w*16 + q*4;
  float* red = Cs;    // scratch: [type][wave*128 + col]
  #pragma unroll
  for (int nt = 0; nt < 8; ++nt) {
    float bv = b1[nt*16 + m];
    float sum = 0.f, sq = 0.f;
    #pragma unroll
    for (int i = 0; i < 4; ++i) {
      if (rbase + i < N) acc[nt][i] += bv; else acc[nt][i] = 0.f;
      sum += acc[nt][i]; sq += acc[nt][i]*acc[nt][i];
    }
    sum += __shfl_xor(sum, 16); sum += __shfl_xor(sum, 32);
    sq  += __shfl_xor(sq, 16);  sq  += __shfl_xor(sq, 32);
    if (l < 16) {
      red[      w*128 + nt*16 + l] = sum;
      red[512 + w*128 + nt*16 + l] = sq;
    }
  }
  __syncthreads();
  {
    int type = tid >> 7, col = tid & 127;
    float v = red[type*512 + col] + red[type*512 + 128 + col]
            + red[type*512 + 256 + col] + red[type*512 + 384 + col];
    partial[((size_t)seg*gridDim.x + blockIdx.x)*256 + tid] = v;
  }
  __syncthreads();
  #pragma unroll
  for (int nt = 0; nt < 8; ++nt)
    #pragma unroll
    for (int i = 0; i < 4; ++i)
      Cs[(w*16 + q*4 + i)*STRCF + nt*16 + m] = acc[nt][i];
  __syncthreads();
  const int ar = tid >> 2, p = tid & 3;
  const int r = r0 + ar;
  u16* __restrict__ P = seg ? Py : Px;
  if (r < N) {
    const float* sp = &Cs[ar*STRCF + p*32];
    u16* dp = P + (size_t)r*DD + p*32;
    #pragma unroll
    for (int i = 0; i < 4; ++i) {
      bf16x8 ob;
      #pragma unroll
      for (int t2 = 0; t2 < 8; ++t2) ob[t2] = (short)f2bf(sp[i*8+t2]);
      *(bf16x8*)(dp + i*8) = ob;
    }
  }
}

// K5b: reduce per-block partials into stats (few atomics).
__global__ __launch_bounds__(256) void k5b_stats(
    const float* __restrict__ partial, float* __restrict__ stats, int nb)
{
  int seg = blockIdx.y, chunk = blockIdx.x, t = threadIdx.x;
  int per = (nb + gridDim.x - 1) / gridDim.x;
  int lo = chunk*per, hi = lo+per; if (hi > nb) hi = nb;
  float s = 0.f;
  const float* p = partial + (size_t)seg*nb*256;
  for (int i = lo; i < hi; ++i) s += p[(size_t)i*256 + t];
  atomicAdd(&stats[seg*256 + t], s);
}

// K6: BN+PReLU (bf16 P) -> MFMA GEMM2 (+b2) -> parallel per-row BYOL cosine ->
// 1 atomic/block. NO device fence (R1 lesson: per-block __threadfence = L2
// writeback x1564 = +25us). As unioned with Cs -> ~35KB LDS -> 4 blocks/CU.
__global__ __launch_bounds__(256) void k6_gemm_loss(
    const u16* __restrict__ Px, const u16* __restrict__ Py,
    const u16* __restrict__ AGGb, const float* __restrict__ stats,
    const float* __restrict__ gamma, const float* __restrict__ beta,
    const float* __restrict__ aP, const u16* __restrict__ W2swz,
    const float* __restrict__ b2, float* __restrict__ gloss, int N)
{
  __shared__ __align__(16) float Cs[64*STRCF];   // 33792B; aliased as As (17408B)
  u16* As = (u16*)Cs;
  __shared__ float s1s[128], s2s[128];
  __shared__ float gred[4];
  const int tid = threadIdx.x;
  const int seg = blockIdx.y;
  const u16* __restrict__ P = seg ? Py : Px;
  const int toff = seg ? 128 : 384;  // seg0: target_x = s3; seg1: target_y = s1
  const float invN = 1.f / (float)N;
  if (tid < 128) {
    float mu = stats[seg*256 + tid] * invN;
    float var = stats[seg*256 + 128 + tid] * invN - mu*mu;
    float rstd = rsqrtf(var + 1e-5f);
    float s1 = rstd * gamma[tid];
    s1s[tid] = s1;
    s2s[tid] = beta[tid] - mu*s1;
  }
  const float alpha = aP[0];
  const int r0 = blockIdx.x * 64;
  __syncthreads();
  #pragma unroll
  for (int i = 0; i < 4; ++i) {
    int f = tid + 256*i;
    int row = f >> 4, c8 = f & 15;
    int r = r0 + row;
    bf16x8 ch = {0,0,0,0,0,0,0,0};
    if (r < N) ch = *(const bf16x8*)(P + (size_t)r*DD + c8*8);
    bf16x8 a;
    #pragma unroll
    for (int t2 = 0; t2 < 8; ++t2) {
      int colc = c8*8 + t2;
      float hv = bf2f((u16)ch[t2]);
      float hn = hv*s1s[colc] + s2s[colc];
      hn = hn >= 0.f ? hn : alpha*hn;
      a[t2] = (short)f2bf(hn);
    }
    *(bf16x8*)&As[row*STRA + c8*8] = a;
  }
  __syncthreads();
  const int w = tid >> 6, l = tid & 63;
  const int m = l & 15, q = l >> 4;
  f32x4 acc[8];
  #pragma unroll
  for (int nt = 0; nt < 8; ++nt) acc[nt] = (f32x4){0.f,0.f,0.f,0.f};
  const int arow = w*16 + m;
  #pragma unroll
  for (int kt = 0; kt < 4; ++kt) {
    bf16x8 af = *(const bf16x8*)&As[arow*STRA + kt*32 + q*8];
    #pragma unroll
    for (int nt = 0; nt < 8; ++nt) {
      bf16x8 bf = *(const bf16x8*)(W2swz + ((size_t)(kt*8+nt)*64 + l)*8);
      acc[nt] = __builtin_amdgcn_mfma_f32_16x16x32_bf16(af, bf, acc[nt], 0, 0, 0);
    }
  }
  __syncthreads();                  // As dead; Cs writes follow (aliased)
  #pragma unroll
  for (int nt = 0; nt < 8; ++nt) {
    float bv = b2[nt*16 + m];
    #pragma unroll
    for (int i = 0; i < 4; ++i)
      Cs[(w*16 + q*4 + i)*STRCF + nt*16 + m] = acc[nt][i] + bv;
  }
  __syncthreads();
  // Parallel BYOL cosine: 4 lanes per row (lane 4r+q covers 32 cols).
  // After xor1+xor2 all 4 lanes of a row hold full sums; the xor4..32 tree
  // sums each row exactly ONCE per qq-group (no /4 — that was the R2 bug).
  {
    const int rt = tid >> 2, qq = tid & 3;
    const int r = r0 + rt;
    float pp = 0.f, tt = 0.f, pt = 0.f;
    if (r < N) {
      const float* prow = &Cs[rt*STRCF + qq*32];
      const u16* trow = AGGb + (size_t)r*512 + toff + qq*32;
      #pragma unroll
      for (int i = 0; i < 4; ++i) {
        float4 pa = *(const float4*)(prow + i*8);
        float4 pb = *(const float4*)(prow + i*8 + 4);
        uint4 twv = *(const uint4*)(trow + i*8);
        float t0=bflo(twv.x), t1=bfhi(twv.x), t2=bflo(twv.y), t3=bfhi(twv.y);
        float t4=bflo(twv.z), t5=bfhi(twv.z), t6=bflo(twv.w), t7=bfhi(twv.w);
        pp += pa.x*pa.x + pa.y*pa.y + pa.z*pa.z + pa.w*pa.w
            + pb.x*pb.x + pb.y*pb.y + pb.z*pb.z + pb.w*pb.w;
        tt += t0*t0 + t1*t1 + t2*t2 + t3*t3 + t4*t4 + t5*t5 + t6*t6 + t7*t7;
        pt += pa.x*t0 + pa.y*t1 + pa.z*t2 + pa.w*t3
            + pb.x*t4 + pb.y*t5 + pb.z*t6 + pb.w*t7;
      }
    }
    pp += __shfl_xor(pp, 1); pp += __shfl_xor(pp, 2);
    tt += __shfl_xor(tt, 1); tt += __shfl_xor(tt, 2);
    pt += __shfl_xor(pt, 1); pt += __shfl_xor(pt, 2);
    float lsum = (r < N) ? (2.f - 2.f * pt * rsqrtf(pp * tt)) : 0.f;
    lsum += __shfl_xor(lsum, 4);  lsum += __shfl_xor(lsum, 8);
    lsum += __shfl_xor(lsum, 16); lsum += __shfl_xor(lsum, 32);
    if (l == 0) gred[w] = lsum;    // qq=0 group: 16 distinct rows, once each
  }
  __syncthreads();
  if (tid == 0) atomicAdd(gloss, gred[0]+gred[1]+gred[2]+gred[3]);
}

__global__ void k7_loss(const float* __restrict__ gloss, float* __restrict__ out, int N, int total)
{
  out[total] = gloss[0] / (float)N;
}

extern "C" void kernel_launch(void* const* d_in, const int* in_sizes, int n_in,
                              void* d_out, int out_size, void* d_ws, size_t ws_size,
                              hipStream_t stream)
{
  const float* x    = (const float*)d_in[0];
  const float* perb = (const float*)d_in[1];
  const int*   erow = (const int*)d_in[2];
  const int*   ecol = (const int*)d_in[3];
  const float* eval_= (const float*)d_in[4];
  const float* W    = (const float*)d_in[5];
  const float* b    = (const float*)d_in[6];
  const float* Wt   = (const float*)d_in[7];
  const float* bt   = (const float*)d_in[8];
  const float* W1   = (const float*)d_in[9];
  const float* b1   = (const float*)d_in[10];
  const float* gam  = (const float*)d_in[11];
  const float* bet  = (const float*)d_in[12];
  const float* aP   = (const float*)d_in[13];
  const float* W2   = (const float*)d_in[14];
  const float* b2   = (const float*)d_in[15];
  const int N = in_sizes[0] / DD;
  const int E = in_sizes[2];
  const int NB5 = (N + 63)/64;

  char* ws = (char*)d_ws;
  size_t off = 0;
  auto alloc = [&](size_t bytes) -> void* {
    void* p = ws + off;
    off += (bytes + 255) & ~(size_t)255;
    return p;
  };
  u16*   AGGb = (u16*)  alloc((size_t)N*512*sizeof(u16));   // 51.2 MB (bf16)
  u16*   T    = (u16*)  alloc((size_t)N*256*sizeof(u16));   // 25.6 MB (reused as Px/Py)
  u16*   T2   = (u16*)  alloc((size_t)N*256*sizeof(u16));   // 25.6 MB
  int*   deg  = (int*)  alloc((size_t)N*sizeof(int));
  float* stats= (float*)alloc(512*sizeof(float));
  float* gloss= (float*)alloc(256);
  int*   ovfc = (int*)((char*)gloss + 64);
  int2*  perm = (int2*) alloc((size_t)N*CAP*sizeof(int2));  // 25.6 MB
  int*   ovf  = (int*)  alloc(4096*sizeof(int));
  u16*   Bswz = (u16*)  alloc(32768*sizeof(u16));
  u16*   W1swz= (u16*)  alloc(16384*sizeof(u16));
  u16*   W2swz= (u16*)  alloc(16384*sizeof(u16));
  float* partial = (float*)alloc((size_t)2*NB5*256*sizeof(float)); // 1.6 MB
  if (ws_size < off) return;

  u16* Px = T;                       // T dead after k4; 2 x 12.8 MB bf16
  u16* Py = Px + (size_t)N*DD;

  kU_init<<<(N*32 + 255)/256, 256, 0, stream>>>(x, perb, W, Wt, W1, W2,
                                                T, Bswz, W1swz, W2swz,
                                                deg, stats, gloss, N);
  k2_bucket<<<(E + 255)/256, 256, 0, stream>>>(erow, ecol, eval_, E, deg, perm, ovfc, ovf);
  k3_spmm<<<(N + 3)/4, 256, 0, stream>>>(perm, deg, T, T2, N);
  k3b_ovf<<<1, 256, 0, stream>>>(erow, ecol, eval_, ovfc, ovf, T, T2);
  k4_gemm<<<(N + 31)/32, 256, 0, stream>>>(T2, Bswz, b, bt, T, AGGb, (float*)d_out, N);
  k5_gemm<<<dim3(NB5, 2), 256, 0, stream>>>(AGGb, W1swz, b1, Px, Py, partial, N);
  k5b_stats<<<dim3(16, 2), 256, 0, stream>>>(partial, stats, NB5);
  k6_gemm_loss<<<dim3(NB5, 2), 256, 0, stream>>>(Px, Py, AGGb, stats, gam, bet, aP,
                                                 W2swz, b2, gloss, N);
  k7_loss<<<1, 1, 0, stream>>>(gloss, (float*)d_out, N, N*DD);
}

// Round 4
// 332.120 us; speedup vs baseline: 1.1542x; 1.0058x over previous
//
#include <hip/hip_runtime.h>
#include <hip/hip_fp16.h>
#include <stdint.h>

typedef unsigned short u16;
typedef unsigned int u32;
typedef __attribute__((ext_vector_type(8))) short bf16x8;
typedef __attribute__((ext_vector_type(4))) short bf16x4;
typedef __attribute__((ext_vector_type(4))) float f32x4;

#define DD 128
#define CAP 64     // Poisson(16): P(deg>64) ~ 1e-20; overflow path still correct
#define STRA 136   // A-tile LDS stride (u16): 272B rows, 16B-aligned
#define STRC1 264  // C-tile stride (u16); STRC1*2B == STRCF*4B == 528B rows
#define STRCF 132  // f32 C-tile stride

__device__ __forceinline__ float bflo(u32 u){ return __uint_as_float(u<<16); }
__device__ __forceinline__ float bfhi(u32 u){ return __uint_as_float(u & 0xffff0000u); }
__device__ __forceinline__ float bf2f(u16 u){ return __uint_as_float(((u32)u)<<16); }
__device__ __forceinline__ u16 f2bf(float f){
  u32 u = __float_as_uint(f);
  return (u16)((u + 0x7fffu + ((u>>16)&1u)) >> 16);   // RNE
}

#define FMA8(g, vv) do { \
    acc[0] += (vv)*bflo((g).x); acc[1] += (vv)*bfhi((g).x); \
    acc[2] += (vv)*bflo((g).y); acc[3] += (vv)*bfhi((g).y); \
    acc[4] += (vv)*bflo((g).z); acc[5] += (vv)*bfhi((g).z); \
    acc[6] += (vv)*bflo((g).w); acc[7] += (vv)*bfhi((g).w); } while(0)

// kU: fused init. (a) zero control region (COMPUTE kernel, never SDMA/memset —
// graph replay ordering), (b) pre-swizzle weights into MFMA B-fragment order,
// (c) build gather table T[r] = [bf16(x_r) (128) | bf16(perb_r) (128)].
__global__ __launch_bounds__(256) void kU_init(
    const float* __restrict__ x, const float* __restrict__ perb,
    const float* __restrict__ W, const float* __restrict__ Wt,
    const float* __restrict__ W1, const float* __restrict__ W2,
    u16* __restrict__ T, u16* __restrict__ Bswz,
    u16* __restrict__ W1swz, u16* __restrict__ W2swz,
    int* __restrict__ deg, float* __restrict__ stats,
    float* __restrict__ gbuf, int N)
{
  int f = blockIdx.x*256 + threadIdx.x;
  if (f < N) deg[f] = 0;
  if (f < 512) stats[f] = 0.f;
  if (f < 64) gbuf[f] = 0.f;   // covers gloss + ovfc (256B block)
  if (f < 65536) {
    int idx = f;
    if (idx < 32768) {
      int j = idx & 7, lane = (idx>>3)&63, nt = (idx>>9)&15, kt = idx>>13;
      int k = kt*32 + (lane>>4)*8 + j, n = nt*16 + (lane&15);
      float v = (n < DD) ? W[k*DD + n] : Wt[k*DD + (n-DD)];
      Bswz[idx] = f2bf(v);
    } else {
      int t = idx - 32768;
      int which = t >> 14; t &= 16383;
      int j = t & 7, lane = (t>>3)&63, nt = (t>>9)&7, kt = (t>>12)&3;
      int k = kt*32 + (lane>>4)*8 + j, n = nt*16 + (lane&15);
      const float* __restrict__ src = which ? W2 : W1;
      u16* __restrict__ dst = which ? W2swz : W1swz;
      dst[t] = f2bf(src[k*DD + n]);
    }
  }
  if (f < N*32) {
    int r = f >> 5, c8 = f & 31;
    const float* src = (c8 < 16) ? (x + (size_t)r*DD + c8*8)
                                 : (perb + (size_t)r*DD + (c8-16)*8);
    float4 a = *(const float4*)src;
    float4 bq = *(const float4*)(src + 4);
    bf16x8 o;
    o[0]=(short)f2bf(a.x); o[1]=(short)f2bf(a.y); o[2]=(short)f2bf(a.z); o[3]=(short)f2bf(a.w);
    o[4]=(short)f2bf(bq.x); o[5]=(short)f2bf(bq.y); o[6]=(short)f2bf(bq.z); o[7]=(short)f2bf(bq.w);
    *(bf16x8*)(T + (size_t)r*256 + c8*8) = o;
  }
}

// K2: bucket edges by destination row. Packed 4B/edge: col:u16 | val:f16
// (N<65536; f16 rel err 5e-4 -> negligible). Halves scatter traffic; each
// row's 64 slots now fit one 64B line region (256B).
__global__ __launch_bounds__(256) void k2_bucket(
    const int* __restrict__ row, const int* __restrict__ col,
    const float* __restrict__ val, int E, int* __restrict__ deg,
    u32* __restrict__ perm, int* __restrict__ ovfc, int* __restrict__ ovf)
{
  int e = blockIdx.x*256 + threadIdx.x;
  if (e >= E) return;
  int r = row[e];
  int slot = atomicAdd(&deg[r], 1);
  if (slot < CAP) {
    u32 pk = (u32)(col[e] & 0xffff)
           | ((u32)__half_as_ushort(__float2half(val[e])) << 16);
    perm[(size_t)r*CAP + slot] = pk;
  }
  else { int oi = atomicAdd(ovfc, 1); if (oi < 4096) ovf[oi] = e; }
}

// K3: one wave per row. dwordx4 gathers: 32 lanes cover one 512B T-row,
// two wave-halves process even/odd edges. Bound by random-gather memory
// throughput (R0 vs R1: halving VMEM instrs left dur unchanged).
// Output T2[r] = [aggx1 (128) | aggx2=aggx1+aggp (128)] bf16 (no bias).
__global__ __launch_bounds__(256) void k3_spmm(
    const u32* __restrict__ perm, const int* __restrict__ deg,
    const u16* __restrict__ T, u16* __restrict__ T2, int N)
{
  int row = blockIdx.x*4 + (threadIdx.x >> 6);
  int l = threadIdx.x & 63;
  if (row >= N) return;
  int dg = deg[row];
  dg = dg < 0 ? 0 : (dg > CAP ? CAP : dg);       // defensive clamp
  const int half = l >> 5, hl = l & 31;
  const int eoff = hl * 8;                        // elem offset in 256-wide T row
  float acc[8] = {0.f,0.f,0.f,0.f,0.f,0.f,0.f,0.f};
  for (int base = 0; base < dg; base += 64) {
    u32 pk = 0;                                   // pad: c=0, v=0 (harmless gather)
    if (base + l < dg) pk = perm[(size_t)row*CAP + base + l];
    int mm = dg - base; if (mm > 64) mm = 64;
    int kmax = (mm + 1) & ~1;                     // round up to even (pad v=0)
    int j = 0;
    for (; j + 8 <= kmax; j += 8) {
      u32 p0 = (u32)__shfl((int)pk, j + half);
      u32 p1 = (u32)__shfl((int)pk, j + 2 + half);
      u32 p2 = (u32)__shfl((int)pk, j + 4 + half);
      u32 p3 = (u32)__shfl((int)pk, j + 6 + half);
      int c0 = p0 & 0xffff; c0 = (c0 < N) ? c0 : 0;
      int c1 = p1 & 0xffff; c1 = (c1 < N) ? c1 : 0;
      int c2 = p2 & 0xffff; c2 = (c2 < N) ? c2 : 0;
      int c3 = p3 & 0xffff; c3 = (c3 < N) ? c3 : 0;
      float v0 = __half2float(__ushort_as_half((u16)(p0 >> 16)));
      float v1 = __half2float(__ushort_as_half((u16)(p1 >> 16)));
      float v2 = __half2float(__ushort_as_half((u16)(p2 >> 16)));
      float v3 = __half2float(__ushort_as_half((u16)(p3 >> 16)));
      uint4 g0 = *(const uint4*)(T + (size_t)c0*256 + eoff);
      uint4 g1 = *(const uint4*)(T + (size_t)c1*256 + eoff);
      uint4 g2 = *(const uint4*)(T + (size_t)c2*256 + eoff);
      uint4 g3 = *(const uint4*)(T + (size_t)c3*256 + eoff);
      FMA8(g0, v0); FMA8(g1, v1); FMA8(g2, v2); FMA8(g3, v3);
    }
    for (; j < kmax; j += 2) {
      u32 p0 = (u32)__shfl((int)pk, j + half);
      int c0 = p0 & 0xffff; c0 = (c0 < N) ? c0 : 0;
      float v0 = __half2float(__ushort_as_half((u16)(p0 >> 16)));
      uint4 g0 = *(const uint4*)(T + (size_t)c0*256 + eoff);
      FMA8(g0, v0);
    }
  }
  // combine even/odd-edge partials across halves
  #pragma unroll
  for (int i = 0; i < 8; ++i) acc[i] += __shfl_xor(acc[i], 32);
  // hl<16 holds x-part elems (aggx1), hl>=16 holds perb-part elems;
  // aggx2[e] = aggx1[e] + aggp[e]: fetch partner-x from lane hl-16.
  int sel = (hl >= 16) ? (hl - 16) : hl;
  bf16x8 ob;
  #pragma unroll
  for (int i = 0; i < 8; ++i) {
    float xv = __shfl(acc[i], sel);
    float o = (hl < 16) ? acc[i] : (xv + acc[i]);
    ob[i] = (short)f2bf(o);
  }
  if (half == 0)
    *(bf16x8*)(T2 + (size_t)row*256 + hl*8) = ob;   // 32 lanes x 16B = 512B row
}

// K3b: overflow fallback (expected empty) — serial RMW on T2 (raw edges).
__global__ __launch_bounds__(256) void k3b_ovf(
    const int* __restrict__ rowI, const int* __restrict__ colI,
    const float* __restrict__ val, const int* __restrict__ ovfc,
    const int* __restrict__ ovf, const u16* __restrict__ T,
    u16* __restrict__ T2)
{
  int n = *ovfc; if (n > 4096) n = 4096;
  for (int i = 0; i < n; ++i) {
    int e = ovf[i];
    int r = rowI[e], c = colI[e];
    float v = val[e];
    int d = threadIdx.x;           // 256 threads cover the 256-wide row
    int dl = d & 127;
    float add = v * bf2f(T[(size_t)c*256 + dl]);
    if (d >= 128) add += v * bf2f(T[(size_t)c*256 + 128 + dl]);
    u16* p = &T2[(size_t)r*256 + d];
    *p = f2bf(bf2f(*p) + add);
  }
}

// K4 (fused k4+k5): stage1: [aggx1;aggx2] @ [W|Wt] + bias (MFMA, 64x256).
//   -> AGGb[r] = [s1|s3] (targets only, bf16, 256 u16/row)
//   -> embed = x+perb+s2 (fp32, from bf16 table T)
// stage2: P = bf16(s0|s2 + b) @ W1 + b1 (MFMA, reading stage1 C-tile
//   DIRECTLY from LDS) -> Px/Py bf16 + per-block BN partials.
// Eliminates k5's 51.2MB AGGb re-read + 25.6MB of AGGb writes + 1 launch.
__global__ __launch_bounds__(256) void k4_gemm(
    const u16* __restrict__ T2, const u16* __restrict__ Bswz,
    const u16* __restrict__ W1swz,
    const float* __restrict__ b, const float* __restrict__ bt,
    const float* __restrict__ b1, const u16* __restrict__ T,
    u16* __restrict__ AGGb, float* __restrict__ outE,
    u16* __restrict__ Px, u16* __restrict__ Py,
    float* __restrict__ partial, int N, int NB)
{
  __shared__ __align__(16) u16 As1[64*STRA];      // 17408B
  __shared__ __align__(16) float CsU[64*STRCF];   // 33792B: Cs1(bf16) -> red -> Cs2(f32)
  u16* Cs1 = (u16*)CsU;
  const int tid = threadIdx.x;
  const int r0 = blockIdx.x * 32;
  // ---- load A (64 rows: 0-31 = aggx1, 32-63 = aggx2) ----
  #pragma unroll
  for (int i = 0; i < 4; ++i) {
    int f = tid + 256*i;            // 1024 chunks: 64 A-rows x 16 chunks of 8
    int row = f >> 4, c8 = f & 15;
    int r = r0 + (row & 31);
    bf16x8 ch = {0,0,0,0,0,0,0,0};
    if (r < N) ch = *(const bf16x8*)(T2 + (size_t)r*256 + (row>>5)*128 + c8*8);
    *(bf16x8*)&As1[row*STRA + c8*8] = ch;
  }
  __syncthreads();
  const int w = tid >> 6, l = tid & 63;
  const int m = l & 15, q = l >> 4;
  // ---- stage1 MFMA: 64x256 ----
  {
    f32x4 acc[16];
    #pragma unroll
    for (int nt = 0; nt < 16; ++nt) acc[nt] = (f32x4){0.f,0.f,0.f,0.f};
    const int arow = w*16 + m;
    #pragma unroll
    for (int kt = 0; kt < 4; ++kt) {
      bf16x8 af = *(const bf16x8*)&As1[arow*STRA + kt*32 + q*8];
      #pragma unroll
      for (int nt = 0; nt < 16; ++nt) {
        bf16x8 bfr = *(const bf16x8*)(Bswz + ((size_t)(kt*16+nt)*64 + l)*8);
        acc[nt] = __builtin_amdgcn_mfma_f32_16x16x32_bf16(af, bfr, acc[nt], 0, 0, 0);
      }
    }
    #pragma unroll
    for (int nt = 0; nt < 16; ++nt) {
      int n = nt*16 + m;
      float bv = (n < 128) ? b[n] : bt[n-128];
      #pragma unroll
      for (int i = 0; i < 4; ++i)
        Cs1[(w*16 + q*4 + i)*STRC1 + nt*16 + m] = f2bf(acc[nt][i] + bv);
    }
  }
  __syncthreads();
  // ---- AGGb write: [s1|s3] = Cs1 cols 128..255 (rows<32 -> s1, rows>=32 -> s3) ----
  {
    const int ar = tid >> 2, p = tid & 3;
    const int src = r0 + (ar & 31);
    if (src < N) {
      u16* dp = AGGb + (size_t)src*256 + (ar>>5)*128 + p*32;
      const u16* sp = &Cs1[ar*STRC1 + 128 + p*32];
      #pragma unroll
      for (int i = 0; i < 4; ++i)
        *(bf16x8*)(dp + i*8) = *(const bf16x8*)(sp + i*8);
    }
  }
  // ---- embed = x + perb + s2 (rows 32-63 of Cs1, cols 0-127, bias incl.) ----
  #pragma unroll
  for (int i = 0; i < 2; ++i) {
    int f = tid + 256*i;            // 512 chunks: 32 rows x 16 chunks of 8
    int rr = f >> 4, c8 = f & 15;
    int src = r0 + rr;
    if (src < N) {
      const u16* cp = &Cs1[(32+rr)*STRC1 + c8*8];
      bf16x8 xv = *(const bf16x8*)(T + (size_t)src*256 + c8*8);
      bf16x8 pv = *(const bf16x8*)(T + (size_t)src*256 + 128 + c8*8);
      bf16x8 cv = *(const bf16x8*)cp;
      float4 e0, e1;
      e0.x = bf2f((u16)xv[0])+bf2f((u16)pv[0])+bf2f((u16)cv[0]);
      e0.y = bf2f((u16)xv[1])+bf2f((u16)pv[1])+bf2f((u16)cv[1]);
      e0.z = bf2f((u16)xv[2])+bf2f((u16)pv[2])+bf2f((u16)cv[2]);
      e0.w = bf2f((u16)xv[3])+bf2f((u16)pv[3])+bf2f((u16)cv[3]);
      e1.x = bf2f((u16)xv[4])+bf2f((u16)pv[4])+bf2f((u16)cv[4]);
      e1.y = bf2f((u16)xv[5])+bf2f((u16)pv[5])+bf2f((u16)cv[5]);
      e1.z = bf2f((u16)xv[6])+bf2f((u16)pv[6])+bf2f((u16)cv[6]);
      e1.w = bf2f((u16)xv[7])+bf2f((u16)pv[7])+bf2f((u16)cv[7]);
      float* er = outE + (size_t)src*DD + c8*8;
      *(float4*)er = e0;
      *(float4*)(er+4) = e1;
    }
  }
  // ---- stage2 MFMA: P = Cs1[:, 0:128] @ W1 (A read in-place, stride STRC1) ----
  f32x4 acc2[8];
  #pragma unroll
  for (int nt = 0; nt < 8; ++nt) acc2[nt] = (f32x4){0.f,0.f,0.f,0.f};
  {
    const int arow = w*16 + m;
    #pragma unroll
    for (int kt = 0; kt < 4; ++kt) {
      bf16x8 af = *(const bf16x8*)&Cs1[arow*STRC1 + kt*32 + q*8];
      #pragma unroll
      for (int nt = 0; nt < 8; ++nt) {
        bf16x8 bfr = *(const bf16x8*)(W1swz + ((size_t)(kt*8+nt)*64 + l)*8);
        acc2[nt] = __builtin_amdgcn_mfma_f32_16x16x32_bf16(af, bfr, acc2[nt], 0, 0, 0);
      }
    }
  }
  __syncthreads();                  // all Cs1 reads done; CsU reused as red
  // ---- b1 + validity + BN partial sums ----
  float* red = CsU;                 // [type(2)][wave(4)*128 + col]
  #pragma unroll
  for (int nt = 0; nt < 8; ++nt) {
    float bv = b1[nt*16 + m];
    float sum = 0.f, sq = 0.f;
    #pragma unroll
    for (int i = 0; i < 4; ++i) {
      int src = r0 + ((w*16 + q*4 + i) & 31);
      if (src < N) acc2[nt][i] += bv; else acc2[nt][i] = 0.f;
      sum += acc2[nt][i]; sq += acc2[nt][i]*acc2[nt][i];
    }
    sum += __shfl_xor(sum, 16); sum += __shfl_xor(sum, 32);
    sq  += __shfl_xor(sq, 16);  sq  += __shfl_xor(sq, 32);
    if (l < 16) {
      red[      w*128 + nt*16 + l] = sum;
      red[512 + w*128 + nt*16 + l] = sq;
    }
  }
  __syncthreads();
  {
    // waves 0,1 = rows 0-31 = seg0 (Px); waves 2,3 = rows 32-63 = seg1 (Py)
    int type = tid >> 7, col = tid & 127;
    float v0 = red[type*512 +   0 + col] + red[type*512 + 128 + col];
    float v1 = red[type*512 + 256 + col] + red[type*512 + 384 + col];
    partial[((size_t)0*NB + blockIdx.x)*256 + tid] = v0;
    partial[((size_t)1*NB + blockIdx.x)*256 + tid] = v1;
  }
  __syncthreads();
  // ---- Cs2 (f32) write ----
  #pragma unroll
  for (int nt = 0; nt < 8; ++nt)
    #pragma unroll
    for (int i = 0; i < 4; ++i)
      CsU[(w*16 + q*4 + i)*STRCF + nt*16 + m] = acc2[nt][i];
  __syncthreads();
  // ---- P write: rows 0-31 -> Px[r0+..], rows 32-63 -> Py[r0+..] ----
  {
    const int ar = tid >> 2, p = tid & 3;
    const int src = r0 + (ar & 31);
    if (src < N) {
      const float* sp = &CsU[ar*STRCF + p*32];
      u16* dp = ((ar >> 5) ? Py : Px) + (size_t)src*DD + p*32;
      #pragma unroll
      for (int i = 0; i < 4; ++i) {
        bf16x8 ob;
        #pragma unroll
        for (int t2 = 0; t2 < 8; ++t2) ob[t2] = (short)f2bf(sp[i*8+t2]);
        *(bf16x8*)(dp + i*8) = ob;
      }
    }
  }
}

// K5b: reduce per-block partials into stats (few atomics).
__global__ __launch_bounds__(256) void k5b_stats(
    const float* __restrict__ partial, float* __restrict__ stats, int nb)
{
  int seg = blockIdx.y, chunk = blockIdx.x, t = threadIdx.x;
  int per = (nb + gridDim.x - 1) / gridDim.x;
  int lo = chunk*per, hi = lo+per; if (hi > nb) hi = nb;
  float s = 0.f;
  const float* p = partial + (size_t)seg*nb*256;
  for (int i = lo; i < hi; ++i) s += p[(size_t)i*256 + t];
  atomicAdd(&stats[seg*256 + t], s);
}

// K6: BN+PReLU (bf16 P) -> MFMA GEMM2 (+b2) -> parallel per-row BYOL cosine ->
// 1 atomic/block. NO device fence (R1 lesson). AGGb now [s1|s3] 256 u16/row:
// seg0 target = s3 (off 128), seg1 target = s1 (off 0).
__global__ __launch_bounds__(256) void k6_gemm_loss(
    const u16* __restrict__ Px, const u16* __restrict__ Py,
    const u16* __restrict__ AGGb, const float* __restrict__ stats,
    const float* __restrict__ gamma, const float* __restrict__ beta,
    const float* __restrict__ aP, const u16* __restrict__ W2swz,
    const float* __restrict__ b2, float* __restrict__ gloss, int N)
{
  __shared__ __align__(16) float Cs[64*STRCF];   // 33792B; aliased as As (17408B)
  u16* As = (u16*)Cs;
  __shared__ float s1s[128], s2s[128];
  __shared__ float gred[4];
  const int tid = threadIdx.x;
  const int seg = blockIdx.y;
  const u16* __restrict__ P = seg ? Py : Px;
  const int toff = seg ? 0 : 128;
  const float invN = 1.f / (float)N;
  if (tid < 128) {
    float mu = stats[seg*256 + tid] * invN;
    float var = stats[seg*256 + 128 + tid] * invN - mu*mu;
    float rstd = rsqrtf(var + 1e-5f);
    float s1 = rstd * gamma[tid];
    s1s[tid] = s1;
    s2s[tid] = beta[tid] - mu*s1;
  }
  const float alpha = aP[0];
  const int r0 = blockIdx.x * 64;
  __syncthreads();
  #pragma unroll
  for (int i = 0; i < 4; ++i) {
    int f = tid + 256*i;
    int row = f >> 4, c8 = f & 15;
    int r = r0 + row;
    bf16x8 ch = {0,0,0,0,0,0,0,0};
    if (r < N) ch = *(const bf16x8*)(P + (size_t)r*DD + c8*8);
    bf16x8 a;
    #pragma unroll
    for (int t2 = 0; t2 < 8; ++t2) {
      int colc = c8*8 + t2;
      float hv = bf2f((u16)ch[t2]);
      float hn = hv*s1s[colc] + s2s[colc];
      hn = hn >= 0.f ? hn : alpha*hn;
      a[t2] = (short)f2bf(hn);
    }
    *(bf16x8*)&As[row*STRA + c8*8] = a;
  }
  __syncthreads();
  const int w = tid >> 6, l = tid & 63;
  const int m = l & 15, q = l >> 4;
  f32x4 acc[8];
  #pragma unroll
  for (int nt = 0; nt < 8; ++nt) acc[nt] = (f32x4){0.f,0.f,0.f,0.f};
  const int arow = w*16 + m;
  #pragma unroll
  for (int kt = 0; kt < 4; ++kt) {
    bf16x8 af = *(const bf16x8*)&As[arow*STRA + kt*32 + q*8];
    #pragma unroll
    for (int nt = 0; nt < 8; ++nt) {
      bf16x8 bfr = *(const bf16x8*)(W2swz + ((size_t)(kt*8+nt)*64 + l)*8);
      acc[nt] = __builtin_amdgcn_mfma_f32_16x16x32_bf16(af, bfr, acc[nt], 0, 0, 0);
    }
  }
  __syncthreads();                  // As dead; Cs writes follow (aliased)
  #pragma unroll
  for (int nt = 0; nt < 8; ++nt) {
    float bv = b2[nt*16 + m];
    #pragma unroll
    for (int i = 0; i < 4; ++i)
      Cs[(w*16 + q*4 + i)*STRCF + nt*16 + m] = acc[nt][i] + bv;
  }
  __syncthreads();
  // Parallel BYOL cosine: 4 lanes per row; xor1+xor2 completes row sums;
  // xor4..32 sums 16 distinct rows once per qq-group (no /4 — R2 lesson).
  {
    const int rt = tid >> 2, qq = tid & 3;
    const int r = r0 + rt;
    float pp = 0.f, tt = 0.f, pt = 0.f;
    if (r < N) {
      const float* prow = &Cs[rt*STRCF + qq*32];
      const u16* trow = AGGb + (size_t)r*256 + toff + qq*32;
      #pragma unroll
      for (int i = 0; i < 4; ++i) {
        float4 pa = *(const float4*)(prow + i*8);
        float4 pb = *(const float4*)(prow + i*8 + 4);
        uint4 twv = *(const uint4*)(trow + i*8);
        float t0=bflo(twv.x), t1=bfhi(twv.x), t2=bflo(twv.y), t3=bfhi(twv.y);
        float t4=bflo(twv.z), t5=bfhi(twv.z), t6=bflo(twv.w), t7=bfhi(twv.w);
        pp += pa.x*pa.x + pa.y*pa.y + pa.z*pa.z + pa.w*pa.w
            + pb.x*pb.x + pb.y*pb.y + pb.z*pb.z + pb.w*pb.w;
        tt += t0*t0 + t1*t1 + t2*t2 + t3*t3 + t4*t4 + t5*t5 + t6*t6 + t7*t7;
        pt += pa.x*t0 + pa.y*t1 + pa.z*t2 + pa.w*t3
            + pb.x*t4 + pb.y*t5 + pb.z*t6 + pb.w*t7;
      }
    }
    pp += __shfl_xor(pp, 1); pp += __shfl_xor(pp, 2);
    tt += __shfl_xor(tt, 1); tt += __shfl_xor(tt, 2);
    pt += __shfl_xor(pt, 1); pt += __shfl_xor(pt, 2);
    float lsum = (r < N) ? (2.f - 2.f * pt * rsqrtf(pp * tt)) : 0.f;
    lsum += __shfl_xor(lsum, 4);  lsum += __shfl_xor(lsum, 8);
    lsum += __shfl_xor(lsum, 16); lsum += __shfl_xor(lsum, 32);
    if (l == 0) gred[w] = lsum;
  }
  __syncthreads();
  if (tid == 0) atomicAdd(gloss, gred[0]+gred[1]+gred[2]+gred[3]);
}

__global__ void k7_loss(const float* __restrict__ gloss, float* __restrict__ out, int N, int total)
{
  out[total] = gloss[0] / (float)N;
}

extern "C" void kernel_launch(void* const* d_in, const int* in_sizes, int n_in,
                              void* d_out, int out_size, void* d_ws, size_t ws_size,
                              hipStream_t stream)
{
  const float* x    = (const float*)d_in[0];
  const float* perb = (const float*)d_in[1];
  const int*   erow = (const int*)d_in[2];
  const int*   ecol = (const int*)d_in[3];
  const float* eval_= (const float*)d_in[4];
  const float* W    = (const float*)d_in[5];
  const float* b    = (const float*)d_in[6];
  const float* Wt   = (const float*)d_in[7];
  const float* bt   = (const float*)d_in[8];
  const float* W1   = (const float*)d_in[9];
  const float* b1   = (const float*)d_in[10];
  const float* gam  = (const float*)d_in[11];
  const float* bet  = (const float*)d_in[12];
  const float* aP   = (const float*)d_in[13];
  const float* W2   = (const float*)d_in[14];
  const float* b2   = (const float*)d_in[15];
  const int N = in_sizes[0] / DD;
  const int E = in_sizes[2];
  const int NB4 = (N + 31)/32;
  const int NB5 = (N + 63)/64;

  char* ws = (char*)d_ws;
  size_t off = 0;
  auto alloc = [&](size_t bytes) -> void* {
    void* p = ws + off;
    off += (bytes + 255) & ~(size_t)255;
    return p;
  };
  u16*   AGGb = (u16*)  alloc((size_t)N*256*sizeof(u16));   // 25.6 MB [s1|s3]
  u16*   T    = (u16*)  alloc((size_t)N*256*sizeof(u16));   // 25.6 MB
  u16*   T2   = (u16*)  alloc((size_t)N*256*sizeof(u16));   // 25.6 MB
  u16*   Px   = (u16*)  alloc((size_t)N*DD*sizeof(u16));    // 12.8 MB
  u16*   Py   = (u16*)  alloc((size_t)N*DD*sizeof(u16));    // 12.8 MB
  int*   deg  = (int*)  alloc((size_t)N*sizeof(int));
  float* stats= (float*)alloc(512*sizeof(float));
  float* gloss= (float*)alloc(256);
  int*   ovfc = (int*)((char*)gloss + 64);
  u32*   perm = (u32*)  alloc((size_t)N*CAP*sizeof(u32));   // 12.8 MB packed
  int*   ovf  = (int*)  alloc(4096*sizeof(int));
  u16*   Bswz = (u16*)  alloc(32768*sizeof(u16));
  u16*   W1swz= (u16*)  alloc(16384*sizeof(u16));
  u16*   W2swz= (u16*)  alloc(16384*sizeof(u16));
  float* partial = (float*)alloc((size_t)2*NB4*256*sizeof(float)); // 3.2 MB
  if (ws_size < off) return;

  kU_init<<<(N*32 + 255)/256, 256, 0, stream>>>(x, perb, W, Wt, W1, W2,
                                                T, Bswz, W1swz, W2swz,
                                                deg, stats, gloss, N);
  k2_bucket<<<(E + 255)/256, 256, 0, stream>>>(erow, ecol, eval_, E, deg, perm, ovfc, ovf);
  k3_spmm<<<(N + 3)/4, 256, 0, stream>>>(perm, deg, T, T2, N);
  k3b_ovf<<<1, 256, 0, stream>>>(erow, ecol, eval_, ovfc, ovf, T, T2);
  k4_gemm<<<NB4, 256, 0, stream>>>(T2, Bswz, W1swz, b, bt, b1, T,
                                   AGGb, (float*)d_out, Px, Py, partial, N, NB4);
  k5b_stats<<<dim3(16, 2), 256, 0, stream>>>(partial, stats, NB4);
  k6_gemm_loss<<<dim3(NB5, 2), 256, 0, stream>>>(Px, Py, AGGb, stats, gam, bet, aP,
                                                 W2swz, b2, gloss, N);
  k7_loss<<<1, 1, 0, stream>>>(gloss, (float*)d_out, N, N*DD);
}